// Round 1
// baseline (11753.844 us; speedup 1.0000x reference)
//
#include <hip/hip_runtime.h>
#include <hip/hip_bf16.h>

// LiquidRNN on MI355X.
// Reformulation: u_t = [x_t; h_t] @ Mfull + c,  Mfull = Wb @ Wh  (768x512),
//                c = bb @ Wh + bh;  d = tanh(u);  h += (d - h) / tau.
// (Exact reassociation: no nonlinearity between the reference's two matmuls.)
//
// k_prep : Mfull (fp32), c, 1/tau                       [~25 us]
// k_frag : Mfull -> bf16 in MFMA A-operand fragment order [~5 us]
// k_rnn  : 64 WGs (one per batch) x 512 threads; 1024 sequential steps;
//          per step: one [1,768]x[768,512] via mfma_f32_16x16x32_bf16,
//          Mfrag streamed from L2 directly into MFMA A operands,
//          [x;h] vector broadcast as B operand from LDS.

#define B_  64
#define S_  1024
#define D_  256
#define H_  512
#define KT_ 768   // D_+H_
#define NKC_ 24   // KT_/32 k-chunks

typedef __attribute__((ext_vector_type(4))) float f32x4;
typedef __attribute__((ext_vector_type(8))) short bf16x8;
typedef __attribute__((ext_vector_type(4))) unsigned short u16x4;

static __device__ __forceinline__ unsigned short f2bf(float f) {
    // round-to-nearest-even fp32 -> bf16 (data is never NaN)
    unsigned int x = __float_as_uint(f);
    unsigned int r = (x + 0x7fffu + ((x >> 16) & 1u)) >> 16;
    return (unsigned short)r;
}

// ---------------- k_prep: Mfull = Wb@Wh, c = bb@Wh + bh, itau = 1/tau ----------
__global__ void k_prep(const float* __restrict__ Wb, const float* __restrict__ bb,
                       const float* __restrict__ Wh, const float* __restrict__ bh,
                       const float* __restrict__ tau,
                       float* __restrict__ Mfull, float* __restrict__ c,
                       float* __restrict__ itau) {
    int i = blockIdx.x * 256 + threadIdx.x;
    if (i < KT_ * H_) {
        int r = i >> 9, n = i & 511;           // Mfull[r][n], r<768, n<512
        float acc = 0.f;
        for (int u = 0; u < 512; ++u)
            acc += Wb[r * 512 + u] * Wh[u * 512 + n];  // coalesced over n
        Mfull[i] = acc;
    } else if (i < KT_ * H_ + 512) {
        int n = i - KT_ * H_;
        float acc = bh[n];
        for (int u = 0; u < 512; ++u)
            acc += bb[u] * Wh[u * 512 + n];
        c[n] = acc;
    } else if (i < KT_ * H_ + 1024) {
        int n = i - KT_ * H_ - 512;
        itau[n] = 1.0f / tau[n];
    }
}

// ---------------- k_frag: fragment-order Mfull as bf16 -------------------------
// Mfrag[((nt*NKC + kc)*64 + lane)*8 + j] = bf16( Mfull[kc*32 + (lane>>4)*8 + j]
//                                                      [nt*16 + (lane&15)] )
// i.e. the verified MFMA A-operand layout A[m=lane&15][k=quad*8+j] for the tile
// A = Mfull^T[nt*16 .. nt*16+15][kc*32 .. kc*32+31].
__global__ void k_frag(const float* __restrict__ Mfull,
                       unsigned short* __restrict__ Mfrag) {
    int F = blockIdx.x * 256 + threadIdx.x;   // < 768*512
    int j = F & 7;
    int lane = (F >> 3) & 63;
    int chunk = F >> 9;                       // nt*NKC + kc
    int kc = chunk % NKC_, nt = chunk / NKC_;
    int r = kc * 32 + ((lane >> 4) << 3) + j;
    int ncol = nt * 16 + (lane & 15);
    Mfrag[F] = f2bf(Mfull[r * 512 + ncol]);
}

// ---------------- k_rnn: the sequential recurrence ------------------------------
__global__ __launch_bounds__(512, 2)
void k_rnn(const float* __restrict__ x, const unsigned short* __restrict__ Mfrag,
           const float* __restrict__ c, const float* __restrict__ itau,
           float* __restrict__ out) {
    __shared__ unsigned short v[2][KT_];   // bf16 [x_t (256); h_t (512)], dbl-buffered
    __shared__ float hf[2][H_];            // fp32 h, dbl-buffered
    __shared__ float cs[H_], ts[H_];

    const int b    = blockIdx.x;
    const int tid  = threadIdx.x;
    const int lane = tid & 63;
    const int w    = tid >> 6;             // wave 0..7, owns ntiles w*4..w*4+3
    const int quad = lane >> 4;
    const int m16  = lane & 15;

    // init: v[0] = [bf16(x_0); zeros], h = 0, stage c and 1/tau
    if (tid < D_) v[0][tid] = f2bf(x[(b * S_) * D_ + tid]);
    v[0][D_ + tid] = 0;
    hf[0][tid] = 0.f;
    cs[tid] = c[tid];
    ts[tid] = itau[tid];
    __syncthreads();

    const bf16x8* Mf = reinterpret_cast<const bf16x8*>(Mfrag);

    for (int t = 0; t < S_; ++t) {
        const int cur = t & 1, nxt = cur ^ 1;

        // prefetch next step's x row (consumed in epilogue, hidden by compute)
        float xn = 0.f;
        const bool xpre = (tid < D_) && (t + 1 < S_);
        if (xpre) xn = x[(b * S_ + t + 1) * D_ + tid];

        f32x4 accs[4];
        #pragma unroll
        for (int nt4 = 0; nt4 < 4; ++nt4) {
            const int nt = w * 4 + nt4;
            // stage all 24 A-fragments (global_load_dwordx4, all in flight)
            bf16x8 mb[NKC_];
            #pragma unroll
            for (int kc = 0; kc < NKC_; ++kc)
                mb[kc] = Mf[(nt * NKC_ + kc) * 64 + lane];
            // two accumulator chains to break mfma latency dependence
            f32x4 a0 = {0.f, 0.f, 0.f, 0.f}, a1 = {0.f, 0.f, 0.f, 0.f};
            #pragma unroll
            for (int kc = 0; kc < NKC_; kc += 2) {
                bf16x8 vf0 = *reinterpret_cast<const bf16x8*>(&v[cur][kc * 32 + quad * 8]);
                bf16x8 vf1 = *reinterpret_cast<const bf16x8*>(&v[cur][(kc + 1) * 32 + quad * 8]);
                a0 = __builtin_amdgcn_mfma_f32_16x16x32_bf16(mb[kc],     vf0, a0, 0, 0, 0);
                a1 = __builtin_amdgcn_mfma_f32_16x16x32_bf16(mb[kc + 1], vf1, a1, 0, 0, 0);
            }
            accs[nt4] = a0 + a1;
        }

        // epilogue: D[row=quad*4+reg][col=m16] = u[nt*16 + quad*4 + reg]
        // (independent of m16: B was broadcast over columns). All lanes compute
        // redundantly; lanes with m16==0 write.
        #pragma unroll
        for (int nt4 = 0; nt4 < 4; ++nt4) {
            const int col0 = (w * 4 + nt4) * 16 + quad * 4;
            f32x4 hn;
            #pragma unroll
            for (int r = 0; r < 4; ++r) {
                const int col = col0 + r;
                float u = accs[nt4][r] + cs[col];
                float e = __expf(2.f * u);
                float d = 1.f - 2.f / (e + 1.f);      // tanh(u), robust at +-inf
                float ho = hf[cur][col];
                hn[r] = ho + (d - ho) * ts[col];
            }
            if (m16 == 0) {
                *reinterpret_cast<f32x4*>(out + (size_t)(b * S_ + t) * H_ + col0) = hn;
                *reinterpret_cast<f32x4*>(&hf[nxt][col0]) = hn;
                u16x4 hb;
                #pragma unroll
                for (int r = 0; r < 4; ++r) hb[r] = f2bf(hn[r]);
                *reinterpret_cast<u16x4*>(&v[nxt][D_ + col0]) = hb;
            }
        }
        if (xpre) v[nxt][tid] = f2bf(xn);
        __syncthreads();   // single barrier per step (everything double-buffered)
    }
}

// ---------------- launch --------------------------------------------------------
extern "C" void kernel_launch(void* const* d_in, const int* in_sizes, int n_in,
                              void* d_out, int out_size, void* d_ws, size_t ws_size,
                              hipStream_t stream) {
    const float* x   = (const float*)d_in[0];  // [64,1024,256]
    const float* Wb  = (const float*)d_in[1];  // [768,512]
    const float* bb  = (const float*)d_in[2];  // [512]
    const float* Wh  = (const float*)d_in[3];  // [512,512]
    const float* bh  = (const float*)d_in[4];  // [512]
    const float* tau = (const float*)d_in[5];  // [512]
    float* out = (float*)d_out;                // [64,1024,512] fp32

    char* ws = (char*)d_ws;
    float*          Mfull = (float*)ws;                              // 1572864 B
    unsigned short* Mfrag = (unsigned short*)(ws + 1572864);         //  786432 B
    float*          c     = (float*)(ws + 1572864 + 786432);         //    2048 B
    float*          it    = (float*)(ws + 1572864 + 786432 + 2048);  //    2048 B

    hipLaunchKernelGGL(k_prep, dim3(1540), dim3(256), 0, stream,
                       Wb, bb, Wh, bh, tau, Mfull, c, it);
    hipLaunchKernelGGL(k_frag, dim3(1536), dim3(256), 0, stream, Mfull, Mfrag);
    hipLaunchKernelGGL(k_rnn, dim3(64), dim3(512), 0, stream, x, Mfrag, c, it, out);
}

// Round 2
// 5046.916 us; speedup vs baseline: 2.3289x; 2.3289x over previous
//
#include <hip/hip_runtime.h>
#include <hip/hip_bf16.h>

// LiquidRNN on MI355X — round 2.
// u_t = [x_t; h_t] @ Mfull + c  (Mfull = Wb@Wh, exact reassociation),
// d = tanh(u), h += (d-h)/tau.
//
// Decomposition: WG(g,s) = batch-group g (16 batches) x H-slice s (64 cols).
// 32 WGs x 256 threads; each wave owns 16 output cols; its weight slice
// (24 A-fragments = 96 VGPRs) is REGISTER-RESIDENT for the whole kernel —
// zero weight traffic per step (round 1 was bound at ~29 B/cyc/CU L2 fill
// restreaming 786 KB/step/CU).
// Per-step cross-WG recurrence exchange: bf16 h written in B-fragment layout
// via agent-scope (LLC) stores; per-(group,step) arrival counter; consumers
// spin then agent-scope load 16 KB of h-frags. x-part MFMAs run pre-spin.

#define S_   1024
#define D_   256
#define H_   512
#define KT_  768   // D_+H_
#define NKC_ 24    // KT_/32
#define ARRIV_ 32  // waves per batch-group: 8 slices x 4 waves

typedef __attribute__((ext_vector_type(4))) float f32x4;
typedef __attribute__((ext_vector_type(8))) short bf16x8;
typedef __attribute__((ext_vector_type(4))) unsigned short u16x4;

static __device__ __forceinline__ unsigned short f2bf(float f) {
    unsigned int x = __float_as_uint(f);
    return (unsigned short)((x + 0x7fffu + ((x >> 16) & 1u)) >> 16);
}

// ---------------- k_prep: Mfull = Wb@Wh, c = bb@Wh + bh, itau, zero counters ---
__global__ void k_prep(const float* __restrict__ Wb, const float* __restrict__ bb,
                       const float* __restrict__ Wh, const float* __restrict__ bh,
                       const float* __restrict__ tau,
                       float* __restrict__ Mfull, float* __restrict__ c,
                       float* __restrict__ itau, int* __restrict__ cnt) {
    int i = blockIdx.x * 256 + threadIdx.x;
    if (i < KT_ * H_) {
        int r = i >> 9, n = i & 511;
        float acc = 0.f;
        for (int u = 0; u < 512; ++u)
            acc += Wb[r * 512 + u] * Wh[u * 512 + n];
        Mfull[i] = acc;
    } else if (i < KT_ * H_ + 512) {
        int n = i - KT_ * H_;
        float acc = bh[n];
        for (int u = 0; u < 512; ++u)
            acc += bb[u] * Wh[u * 512 + n];
        c[n] = acc;
    } else if (i < KT_ * H_ + 1024) {
        itau[i - KT_ * H_ - 512] = 1.0f / tau[i - KT_ * H_ - 512];
    } else if (i < KT_ * H_ + 1024 + 4096) {
        cnt[i - KT_ * H_ - 1024] = 0;   // ws is re-poisoned 0xAA every launch
    }
}

// ---------------- k_frag: Mfull -> bf16 MFMA A-operand fragment order ----------
// Mfrag[((nt*NKC+kc)*64+lane)*8+j] = bf16(Mfull[kc*32+(lane>>4)*8+j][nt*16+(lane&15)])
__global__ void k_frag(const float* __restrict__ Mfull,
                       unsigned short* __restrict__ Mfrag) {
    int F = blockIdx.x * 256 + threadIdx.x;
    int j = F & 7;
    int lane = (F >> 3) & 63;
    int chunk = F >> 9;
    int kc = chunk % NKC_, nt = chunk / NKC_;
    int r = kc * 32 + ((lane >> 4) << 3) + j;
    int ncol = nt * 16 + (lane & 15);
    Mfrag[F] = f2bf(Mfull[r * 512 + ncol]);
}

// ---------------- k_rnn2: register-resident weights + LLC handshake ------------
__global__ __launch_bounds__(256, 1)
void k_rnn2(const float* __restrict__ x, const unsigned short* __restrict__ Mfrag,
            const float* __restrict__ c, const float* __restrict__ itau,
            unsigned long long* __restrict__ hbuf, int* __restrict__ cnt,
            float* __restrict__ out) {
    const int g    = blockIdx.x >> 3;      // batch group 0..3
    const int s    = blockIdx.x & 7;       // h-slice 0..7
    const int tid  = threadIdx.x;
    const int w    = tid >> 6;             // wave 0..3
    const int lane = tid & 63;
    const int quad = lane >> 4;
    const int m16  = lane & 15;
    const int nt   = s * 4 + w;            // global 16-col tile 0..31
    const int C0   = nt * 16 + quad * 4;   // this lane's 4 output cols
    const int b    = g * 16 + m16;         // this lane's batch (B-operand n)

    // ---- weights: 24 A-fragments, register-resident (96 VGPRs/lane) ----
    const bf16x8* Mf = reinterpret_cast<const bf16x8*>(Mfrag);
    bf16x8 wreg[NKC_];
    #pragma unroll
    for (int kc = 0; kc < NKC_; ++kc)
        wreg[kc] = Mf[(nt * NKC_ + kc) * 64 + lane];

    const f32x4 cs = *reinterpret_cast<const f32x4*>(c + C0);
    const f32x4 ts = *reinterpret_cast<const f32x4*>(itau + C0);

    // ---- h-store address (B-fragment layout, bf16, 8 B per lane) ----
    // value (batch=m16, h=C0+r): kc'=C0>>5, lane'=m16+16*((C0&31)>>3), j'=C0&7
    const int kcp   = nt >> 1;
    const int lanep = m16 + 16 * (((nt & 1) << 1) + (quad >> 1));
    const int jsel  = (quad & 1);          // which 8B half (j'=0 or 4)

    int* mycnt = cnt + g * 1024;
    f32x4 h_old = {0.f, 0.f, 0.f, 0.f};

    for (int t = 0; t < S_; ++t) {
        // ---- x loads + x-part MFMAs: independent of the sync, run pre-spin ----
        const float* xp = x + ((size_t)b * S_ + t) * D_ + quad * 8;
        f32x4 xa[8], xb[8];
        #pragma unroll
        for (int kc = 0; kc < 8; ++kc) {
            xa[kc] = *reinterpret_cast<const f32x4*>(xp + kc * 32);
            xb[kc] = *reinterpret_cast<const f32x4*>(xp + kc * 32 + 4);
        }
        f32x4 a0 = {0.f, 0.f, 0.f, 0.f}, a1 = {0.f, 0.f, 0.f, 0.f};
        #pragma unroll
        for (int kc = 0; kc < 8; ++kc) {
            bf16x8 xv;
            #pragma unroll
            for (int j = 0; j < 4; ++j) {
                xv[j]     = (short)f2bf(xa[kc][j]);
                xv[j + 4] = (short)f2bf(xb[kc][j]);
            }
            if (kc & 1) a1 = __builtin_amdgcn_mfma_f32_16x16x32_bf16(wreg[kc], xv, a1, 0, 0, 0);
            else        a0 = __builtin_amdgcn_mfma_f32_16x16x32_bf16(wreg[kc], xv, a0, 0, 0, 0);
        }

        // ---- wait for h_t from all 32 waves of this group ----
        if (t > 0) {
            while (__hip_atomic_load(mycnt + (t - 1), __ATOMIC_ACQUIRE,
                                     __HIP_MEMORY_SCOPE_AGENT) < ARRIV_) {}
            // ---- h-fragment loads (LLC) + h-part MFMAs ----
            const unsigned long long* hb = hbuf + (size_t)(g * 2 + (t & 1)) * 16 * 128;
            unsigned long long hl[16][2];
            #pragma unroll
            for (int kc = 0; kc < 16; ++kc) {
                hl[kc][0] = __hip_atomic_load(hb + kc * 128 + lane * 2,
                                              __ATOMIC_RELAXED, __HIP_MEMORY_SCOPE_AGENT);
                hl[kc][1] = __hip_atomic_load(hb + kc * 128 + lane * 2 + 1,
                                              __ATOMIC_RELAXED, __HIP_MEMORY_SCOPE_AGENT);
            }
            #pragma unroll
            for (int kc = 0; kc < 16; ++kc) {
                union { unsigned long long u[2]; bf16x8 v; } hv;
                hv.u[0] = hl[kc][0];
                hv.u[1] = hl[kc][1];
                if (kc & 1) a1 = __builtin_amdgcn_mfma_f32_16x16x32_bf16(wreg[8 + kc], hv.v, a1, 0, 0, 0);
                else        a0 = __builtin_amdgcn_mfma_f32_16x16x32_bf16(wreg[8 + kc], hv.v, a0, 0, 0, 0);
            }
        }

        // ---- epilogue: u -> tanh -> liquid Euler update ----
        f32x4 acc = a0 + a1;
        f32x4 hn;
        u16x4 hb4;
        #pragma unroll
        for (int r = 0; r < 4; ++r) {
            float u = acc[r] + cs[r];
            float e = __expf(2.f * u);
            float d = 1.f - 2.f / (e + 1.f);          // tanh(u), robust at +-inf
            hn[r] = h_old[r] + (d - h_old[r]) * ts[r];
            hb4[r] = f2bf(hn[r]);
        }
        h_old = hn;

        // out[b][t][C0..C0+3] — one dwordx4/lane; quads of a batch cover a 64B line
        *reinterpret_cast<f32x4*>(out + ((size_t)b * S_ + t) * H_ + C0) = hn;

        // h_{t+1} -> exchange buffer (parity (t+1)&1), agent scope (LLC)
        unsigned long long hval;
        __builtin_memcpy(&hval, &hb4, 8);
        unsigned long long* dst = hbuf + (size_t)((g * 2 + ((t + 1) & 1)) * 16 + kcp) * 128
                                       + lanep * 2 + jsel;
        __hip_atomic_store(dst, hval, __ATOMIC_RELAXED, __HIP_MEMORY_SCOPE_AGENT);

        // release: drain stores to the coherence point, then arrive
        asm volatile("s_waitcnt vmcnt(0)" ::: "memory");
        if (lane == 0)
            __hip_atomic_fetch_add(mycnt + t, 1, __ATOMIC_RELAXED,
                                   __HIP_MEMORY_SCOPE_AGENT);
    }
}

// ---------------- launch --------------------------------------------------------
extern "C" void kernel_launch(void* const* d_in, const int* in_sizes, int n_in,
                              void* d_out, int out_size, void* d_ws, size_t ws_size,
                              hipStream_t stream) {
    const float* x   = (const float*)d_in[0];  // [64,1024,256]
    const float* Wb  = (const float*)d_in[1];
    const float* bb  = (const float*)d_in[2];
    const float* Wh  = (const float*)d_in[3];
    const float* bh  = (const float*)d_in[4];
    const float* tau = (const float*)d_in[5];
    float* out = (float*)d_out;                // [64,1024,512] fp32

    char* ws = (char*)d_ws;
    float*              Mfull = (float*)ws;                          // 1,572,864 B
    unsigned short*     Mfrag = (unsigned short*)(ws + 1572864);     //   786,432 B
    float*              c     = (float*)(ws + 2359296);              //     2,048 B
    float*              it    = (float*)(ws + 2361344);              //     2,048 B
    unsigned long long* hbuf  = (unsigned long long*)(ws + 2363392); //   131,072 B
    int*                cnt   = (int*)(ws + 2494464);                //    16,384 B

    hipLaunchKernelGGL(k_prep, dim3(1556), dim3(256), 0, stream,
                       Wb, bb, Wh, bh, tau, Mfull, c, it, cnt);
    hipLaunchKernelGGL(k_frag, dim3(1536), dim3(256), 0, stream, Mfull, Mfrag);
    hipLaunchKernelGGL(k_rnn2, dim3(32), dim3(256), 0, stream,
                       x, Mfrag, c, it, hbuf, cnt, out);
}